// Round 17
// baseline (3902.439 us; speedup 1.0000x reference)
//
#include <hip/hip_runtime.h>
#include <hip/hip_bf16.h>
#include <math.h>

#define DEVI static __device__ __forceinline__

namespace {
constexpr int B = 32, T = 512, H = 1024, E = 300, V = 32000, S = 50;
constexpr int KX = E + H;       // 1324
constexpr int K0 = 2368;        // KX + H + 20 zero-pad  (74 * 32)
constexpr int K1 = 2048;        // H + H                 (64 * 32)
constexpr int MG = V + H;       // 33024 = generator rows + attn-left rows
}

typedef __bf16 bf16x8 __attribute__((ext_vector_type(8)));
typedef float f32x4 __attribute__((ext_vector_type(4)));

DEVI float bf2f(unsigned short u) { union { unsigned int i; float f; } v; v.i = (unsigned int)u << 16; return v.f; }
DEVI unsigned short f2bf(float f) {
  union { float f; unsigned int i; } v; v.f = f;
  unsigned int x = v.i;
  return (unsigned short)((x + 0x7fffu + ((x >> 16) & 1u)) >> 16);
}
// f32 -> fp8 e4m3fn (OCP), RNE, saturate to +-448
DEVI unsigned char f2e4m3(float x) {
  union { float f; unsigned int u; } v;
  v.f = x;
  unsigned int s = (v.u >> 24) & 0x80u;
  v.u &= 0x7FFFFFFFu;
  if (v.f >= 448.0f) return (unsigned char)(s | 0x7E);
  if (v.f < 0.015625f) {
    int q = (int)rintf(v.f * 512.0f);
    return (unsigned char)(s | (unsigned int)q);
  }
  unsigned int u = v.u;
  unsigned int lsb = (u >> 20) & 1u;
  u += 0x0007FFFFu + lsb;
  unsigned int exp = (u >> 23) - 120u;
  unsigned int man = (u >> 20) & 7u;
  return (unsigned char)(s | (exp << 3) | man);
}
// fp8 e4m3 -> f32, exact for normals, subnormals, zero
DEVI float e4m3f(unsigned int u) {
  unsigned int bits = ((u & 0x80u) << 24) | ((u & 0x7Fu) << 20);
  union { unsigned int i; float f; } v; v.i = bits;
  return v.f * 0x1p120f;
}
#if __has_builtin(__builtin_amdgcn_rcpf)
DEVI float frcp(float x) { return __builtin_amdgcn_rcpf(x); }
#else
DEVI float frcp(float x) { return 1.0f / x; }
#endif
DEVI float sigm(float x) { return frcp(1.0f + __expf(-x)); }
DEVI float tanh_(float x) { return 1.0f - 2.0f * frcp(__expf(2.0f * x) + 1.0f); }

// ===== one-time weight casts ==============================================
__global__ __launch_bounds__(256) void k_cast_gen(const float* __restrict__ genW,
    const float* __restrict__ attn_W, unsigned char* __restrict__ Wbig8) {
  size_t i4 = ((size_t)blockIdx.x * 256 + threadIdx.x) * 4;
  if (i4 >= (size_t)MG * H) return;
  int row = (int)(i4 >> 10), k = (int)(i4 & 1023);
  const float* src = row < V ? &genW[((size_t)row << 10) + k]
                             : &attn_W[(size_t)(row - V) * (2 * H) + k];
  float4 v = *(const float4*)src;
  uchar4 o; o.x = f2e4m3(v.x); o.y = f2e4m3(v.y); o.z = f2e4m3(v.z); o.w = f2e4m3(v.w);
  *(uchar4*)&Wbig8[i4] = o;
}

__global__ __launch_bounds__(256) void k_cast_l0(const float* __restrict__ Wih,
    const float* __restrict__ Whh, unsigned short* __restrict__ Wc) {
  int m = blockIdx.x;                       // 4096 rows, m = n*4 + g
  int g = m & 3, n = m >> 2, srow = g * H + n;
  for (int i = threadIdx.x; i < K0 / 4; i += 256) {
    int k = i * 4;
    float4 v;
    if (k < KX) v = *(const float4*)&Wih[(size_t)srow * KX + k];
    else if (k < KX + H) v = *(const float4*)&Whh[(size_t)srow * H + (k - KX)];
    else v = make_float4(0.f, 0.f, 0.f, 0.f);
    ushort4 o; o.x = f2bf(v.x); o.y = f2bf(v.y); o.z = f2bf(v.z); o.w = f2bf(v.w);
    *(ushort4*)&Wc[(size_t)m * K0 + k] = o;
  }
}

__global__ __launch_bounds__(256) void k_cast_l1(const float* __restrict__ Wih,
    const float* __restrict__ Whh, unsigned short* __restrict__ Wc) {
  int m = blockIdx.x;
  int g = m & 3, n = m >> 2, srow = g * H + n;
  for (int i = threadIdx.x; i < K1 / 4; i += 256) {
    int k = i * 4;
    float4 v = (k < H) ? *(const float4*)&Wih[(size_t)srow * H + k]
                       : *(const float4*)&Whh[(size_t)srow * H + (k - H)];
    ushort4 o; o.x = f2bf(v.x); o.y = f2bf(v.y); o.z = f2bf(v.z); o.w = f2bf(v.w);
    *(ushort4*)&Wc[(size_t)m * K1 + k] = o;
  }
}

// attn_W right half -> fp8 [H][H] (for fp8 encproj MFMA)
__global__ __launch_bounds__(256) void k_cast_attnr(const float* __restrict__ attn_W,
                                                    unsigned char* __restrict__ Wr8) {
  size_t i4 = ((size_t)blockIdx.x * 256 + threadIdx.x) * 4;
  if (i4 >= (size_t)H * H) return;
  int n = (int)(i4 >> 10), k = (int)(i4 & 1023);
  float4 v = *(const float4*)&attn_W[(size_t)n * (2 * H) + H + k];
  uchar4 o; o.x = f2e4m3(v.x); o.y = f2e4m3(v.y); o.z = f2e4m3(v.z); o.w = f2e4m3(v.w);
  *(uchar4*)&Wr8[i4] = o;
}

__global__ void k_bias(const float* bih0, const float* bhh0,
                       const float* bih1, const float* bhh1,
                       float* bc0, float* bc1) {
  int idx = blockIdx.x * 256 + threadIdx.x;
  if (idx < 4096) { int g = idx & 3, n = idx >> 2; bc0[idx] = bih0[g * H + n] + bhh0[g * H + n]; }
  else if (idx < 8192) { int m = idx - 4096; int g = m & 3, n = m >> 2; bc1[m] = bih1[g * H + n] + bhh1[g * H + n]; }
}

// enc_out -> fp8 (used by encproj MFMA and per-step ctx reads)
__global__ __launch_bounds__(256) void k_cast_enc(const float* __restrict__ src,
    unsigned char* __restrict__ dst8) {
  size_t i4 = ((size_t)blockIdx.x * 256 + threadIdx.x) * 4;
  if (i4 >= (size_t)B * T * H) return;
  float4 v = *(const float4*)&src[i4];
  uchar4 o8; o8.x = f2e4m3(v.x); o8.y = f2e4m3(v.y); o8.z = f2e4m3(v.z); o8.w = f2e4m3(v.w);
  *(uchar4*)&dst8[i4] = o8;
}

// ===== initial state =======================================================
__global__ __launch_bounds__(256) void k_init(const float* __restrict__ enc_h,
    const float* __restrict__ enc_c, float* __restrict__ cbuf,
    unsigned short* __restrict__ xc0_0, unsigned short* __restrict__ xc0_1,
    unsigned short* __restrict__ xc1_0, unsigned char* __restrict__ hgen8) {
  int idx = blockIdx.x * 256 + threadIdx.x;
  if (idx < 2 * B * H) {
    int l = idx >> 15, r = idx & 32767, b = r >> 10, hh = r & 1023;
    int half = hh >> 9, hr = hh & 511;
    int src = (2 * l + half) * B * (H / 2) + b * (H / 2) + hr;
    cbuf[idx] = enc_c[src];
    float hv = enc_h[src];
    if (l == 0) xc0_0[(size_t)b * K0 + KX + hh] = f2bf(hv);
    else { xc1_0[(size_t)b * K1 + H + hh] = f2bf(hv); hgen8[(size_t)b * H + hh] = f2e4m3(hv); }
  } else if (idx < 2 * B * H + 2 * B * 20) {
    int j = idx - 2 * B * H;
    int p = j / (B * 20), rr = j % (B * 20), b = rr / 20, kk = rr % 20;
    (p ? xc0_1 : xc0_0)[(size_t)b * K0 + KX + H + kk] = 0;
  }
}

// ===== fp8 GEMM core (K=1024): 16 rows x 32 batch per wave =================
DEVI void gemm_tile_fp8(const unsigned char* __restrict__ W, const unsigned char* __restrict__ X,
                        int m0w, int lane, f32x4& acc0, f32x4& acc1) {
  const unsigned char* Wp = W + (size_t)(m0w + (lane & 15)) * 1024 + (lane >> 4) * 8;
  const unsigned char* Xp = X + (size_t)(lane & 15) * 1024 + (lane >> 4) * 8;
#pragma unroll 4
  for (int k0 = 0; k0 < 1024; k0 += 32) {
    long a  = *(const long*)(Wp + k0);
    long b0 = *(const long*)(Xp + k0);
    long b1 = *(const long*)(Xp + 16 * 1024 + k0);
    acc0 = __builtin_amdgcn_mfma_f32_16x16x32_fp8_fp8(a, b0, acc0, 0, 0, 0);
    acc1 = __builtin_amdgcn_mfma_f32_16x16x32_fp8_fp8(a, b1, acc1, 0, 0, 0);
  }
}

// ===== one-time enc projection: fp8 MFMA GEMM, fp8 output ==================
__global__ __launch_bounds__(256) void k_encproj_mfma(const unsigned char* __restrict__ Wr8,
    const unsigned char* __restrict__ Xb8, const float* __restrict__ attn_b,
    unsigned char* __restrict__ encp8) {
  int bid = blockIdx.x;
  int m0 = (bid & 255) * 64;
  int n0 = (bid >> 8) * 64;
  int wv = threadIdx.x >> 6, lane = threadIdx.x & 63;
  int n0w = n0 + wv * 16;
  const unsigned char* Wp = Wr8 + (size_t)(n0w + (lane & 15)) * H + (lane >> 4) * 8;
  const unsigned char* Xp = Xb8 + (size_t)(m0 + (lane & 15)) * H + (lane >> 4) * 8;
  f32x4 acc[4] = {{0.f,0.f,0.f,0.f},{0.f,0.f,0.f,0.f},{0.f,0.f,0.f,0.f},{0.f,0.f,0.f,0.f}};
#pragma unroll 4
  for (int k0 = 0; k0 < H; k0 += 32) {
    long a = *(const long*)(Wp + k0);
#pragma unroll
    for (int g = 0; g < 4; g++) {
      long b = *(const long*)(Xp + (size_t)g * 16 * H + k0);
      acc[g] = __builtin_amdgcn_mfma_f32_16x16x32_fp8_fp8(a, b, acc[g], 0, 0, 0);
    }
  }
  int nbx = n0w + (lane >> 4) * 4;
  f32x4 bi = *(const f32x4*)&attn_b[nbx];
#pragma unroll
  for (int g = 0; g < 4; g++) {
    int m = m0 + g * 16 + (lane & 15);
    f32x4 o = acc[g] + bi;
    uchar4 ob; ob.x = f2e4m3(o[0]); ob.y = f2e4m3(o[1]); ob.z = f2e4m3(o[2]); ob.w = f2e4m3(o[3]);
    *(uchar4*)&encp8[(size_t)m * H + nbx] = ob;
  }
}

// rows < M0 -> out0 (+bias, + optional expsum partials); rows >= M0 -> out1.
__global__ __launch_bounds__(256, 4) void k_gemm_out_fp8(const unsigned char* __restrict__ W,
    const unsigned char* __restrict__ X, const float* __restrict__ bias, int M0,
    float* __restrict__ out0, int ld0, float* __restrict__ out1, int ld1,
    float* __restrict__ part) {
  __shared__ float esum[4][32];
  int wv = threadIdx.x >> 6, lane = threadIdx.x & 63;
  int m0w = blockIdx.x * 64 + wv * 16;
  f32x4 acc0 = {0.f, 0.f, 0.f, 0.f}, acc1 = acc0;
  gemm_tile_fp8(W, X, m0w, lane, acc0, acc1);
  int r0 = m0w + (lane >> 4) * 4;
  int b = lane & 15;
  float s0 = 0.f, s1 = 0.f;
  if (r0 < M0) {
    f32x4 bi = *(const f32x4*)&bias[r0];
    f32x4 o0 = acc0 + bi, o1 = acc1 + bi;
    *(f32x4*)&out0[(size_t)b * ld0 + r0] = o0;
    *(f32x4*)&out0[(size_t)(b + 16) * ld0 + r0] = o1;
    s0 = __expf(o0[0]) + __expf(o0[1]) + __expf(o0[2]) + __expf(o0[3]);
    s1 = __expf(o1[0]) + __expf(o1[1]) + __expf(o1[2]) + __expf(o1[3]);
  } else {
    int r = r0 - M0;
    *(f32x4*)&out1[(size_t)b * ld1 + r] = acc0;
    *(f32x4*)&out1[(size_t)(b + 16) * ld1 + r] = acc1;
  }
  if (part != nullptr && blockIdx.x < V / 64) {
    s0 += __shfl_xor(s0, 16, 64); s0 += __shfl_xor(s0, 32, 64);
    s1 += __shfl_xor(s1, 16, 64); s1 += __shfl_xor(s1, 32, 64);
    if (lane < 16) { esum[wv][lane] = s0; esum[wv][lane + 16] = s1; }
    __syncthreads();
    if (threadIdx.x < 32)
      part[blockIdx.x * 32 + threadIdx.x] =
          esum[0][threadIdx.x] + esum[1][threadIdx.x] + esum[2][threadIdx.x] + esum[3][threadIdx.x];
  }
}

// ===== LSTM (+ optional lsB(s-1) rider in spare CU slots) ==================
// blocks [0,256): lstm GEMM+cell (512 thr).
// blocks [256,512) (if doAux): lsB of step s-1 (tid<256 active).
// NOTE: riders must not touch any buffer this kernel's lstm blocks read.
template <int K>
__global__ __launch_bounds__(512, 2) void k_gemm_lstm(const unsigned short* __restrict__ W,
    const unsigned short* __restrict__ X, const float* __restrict__ bcomb,
    float* __restrict__ c,
    unsigned short* __restrict__ hA, int ldA_, int offA,
    unsigned short* __restrict__ hB, int ldB_, int offB,
    unsigned char* __restrict__ h8,
    int doAux, const float* __restrict__ logitsR, const float* __restrict__ partR,
    float* __restrict__ out, int s) {
  int tid = threadIdx.x;
  if (blockIdx.x >= 256) {
    if (!doAux) return;
    int bx = blockIdx.x - 256;
    // ---- lsB(s-1): logits/part were written by gen(s-1), a prior launch ----
    if (s == 0 || tid >= 256) return;
    __shared__ float red[256];
    int b = bx >> 3, ch = bx & 7;
    float ssum = 0.f;
    for (int i = tid; i < V / 64; i += 256) ssum += partR[i * 32 + b];
    red[tid] = ssum; __syncthreads();
    for (int st = 128; st; st >>= 1) { if (tid < st) red[tid] += red[tid + st]; __syncthreads(); }
    float lse = __logf(red[0]);
    const float* L = logitsR + (size_t)b * V + ch * 4000;
    float* O = out + ((size_t)b * S + (s - 1)) * V + ch * 4000;
    for (int i = tid; i < 1000; i += 256) {
      float4 v = ((const float4*)L)[i];
      ((float4*)O)[i] = make_float4(v.x - lse, v.y - lse, v.z - lse, v.w - lse);
    }
    return;
  }
  __shared__ f32x4 red[8][64][2];   // 16 KB
  int wv = tid >> 6, lane = tid & 63;
  int m0w = blockIdx.x * 16;
  const unsigned short* Wp = W + (size_t)(m0w + (lane & 15)) * K + (lane >> 4) * 8;
  const unsigned short* Xp = X + (size_t)(lane & 15) * K + (lane >> 4) * 8;
  f32x4 acc0 = {0.f, 0.f, 0.f, 0.f}, acc1 = acc0;
#pragma unroll 2
  for (int k0 = wv * 32; k0 < K; k0 += 256) {
    bf16x8 a  = *(const bf16x8*)(Wp + k0);
    bf16x8 b0 = *(const bf16x8*)(Xp + k0);
    bf16x8 b1 = *(const bf16x8*)(Xp + 16 * K + k0);
    acc0 = __builtin_amdgcn_mfma_f32_16x16x32_bf16(a, b0, acc0, 0, 0, 0);
    acc1 = __builtin_amdgcn_mfma_f32_16x16x32_bf16(a, b1, acc1, 0, 0, 0);
  }
  red[wv][lane][0] = acc0;
  red[wv][lane][1] = acc1;
  __syncthreads();
  if (wv == 0) {
    acc0 = red[0][lane][0] + red[1][lane][0] + red[2][lane][0] + red[3][lane][0]
         + red[4][lane][0] + red[5][lane][0] + red[6][lane][0] + red[7][lane][0];
    acc1 = red[0][lane][1] + red[1][lane][1] + red[2][lane][1] + red[3][lane][1]
         + red[4][lane][1] + red[5][lane][1] + red[6][lane][1] + red[7][lane][1];
    int r0 = m0w + (lane >> 4) * 4;
    int n = r0 >> 2;
    f32x4 bi = *(const f32x4*)&bcomb[r0];
#pragma unroll
    for (int f = 0; f < 2; f++) {
      f32x4 g = f ? acc1 : acc0;
      int b = (lane & 15) + f * 16;
      float gi = g[0] + bi[0], gf = g[1] + bi[1];
      float gg = g[2] + bi[2], go = g[3] + bi[3];
      float cp = c[(size_t)b * H + n];
      float c2 = sigm(gf) * cp + sigm(gi) * tanh_(gg);
      c[(size_t)b * H + n] = c2;
      float h2 = sigm(go) * tanh_(c2);
      unsigned short hb = f2bf(h2);
      hA[(size_t)b * ldA_ + offA + n] = hb;
      if (hB) hB[(size_t)b * ldB_ + offB + n] = hb;
      if (h8) h8[(size_t)b * H + n] = f2e4m3(h2);
    }
  }
}

// ===== P1: scores (fp8 encp, 8 t/wave) + embedding gather ==================
// grid 544: [0,512) scores; [512,544) emb(s) into xc0[par] (read later by lstm0).
__global__ __launch_bounds__(256, 4) void k_p1(const unsigned char* __restrict__ encp8,
    const float* __restrict__ hidproj, const float* __restrict__ vvec,
    float* __restrict__ scores,
    const float* __restrict__ embedding, const int* __restrict__ question,
    unsigned short* __restrict__ xc, int s) {
  int bx = blockIdx.x, tid = threadIdx.x;
  if (bx < 512) {
    int wv = tid >> 6, lane = tid & 63;
    int wid0 = bx * 32 + wv * 8;
    int b = wid0 >> 9;
    const float* hp = hidproj + (size_t)b * H + lane * 16;
    const float* vp = vvec + lane * 16;
    float4 h4[4], v4[4];
#pragma unroll
    for (int i = 0; i < 4; i++) { h4[i] = *(const float4*)&hp[i * 4]; v4[i] = *(const float4*)&vp[i * 4]; }
#pragma unroll
    for (int j = 0; j < 8; j++) {
      const unsigned char* ep = encp8 + (size_t)(wid0 + j) * H + lane * 16;
      uint4 u = *(const uint4*)ep;
      float acc = 0.f;
      unsigned int ws[4] = {u.x, u.y, u.z, u.w};
#pragma unroll
      for (int i = 0; i < 4; i++) {
        unsigned int wd = ws[i];
        acc += v4[i].x * tanh_(e4m3f(wd & 0xFF) + h4[i].x);
        acc += v4[i].y * tanh_(e4m3f((wd >> 8) & 0xFF) + h4[i].y);
        acc += v4[i].z * tanh_(e4m3f((wd >> 16) & 0xFF) + h4[i].z);
        acc += v4[i].w * tanh_(e4m3f(wd >> 24) + h4[i].w);
      }
#pragma unroll
      for (int off = 32; off; off >>= 1) acc += __shfl_xor(acc, off, 64);
      if (lane == 0) scores[wid0 + j] = acc;
    }
  } else {
    int b = bx - 512;
    int tok = question[b * S + s];
    for (int e = tid; e < E; e += 256)
      xc[(size_t)b * K0 + e] = f2bf(embedding[(size_t)tok * E + e]);
  }
}

// ===== ctx: softmax over T + weighted sum of fp8 enc columns ===============
__global__ __launch_bounds__(256, 4) void k_ctx(const float* __restrict__ scores,
    const unsigned char* __restrict__ enc8, unsigned short* __restrict__ xc) {
  int b = blockIdx.x, y = blockIdx.y, tid = threadIdx.x;
  __shared__ float aw[T];
  __shared__ float red[256];
  float s0 = scores[b * T + tid], s1 = scores[b * T + 256 + tid];
  float m = fmaxf(s0, s1);
  red[tid] = m; __syncthreads();
  for (int st = 128; st; st >>= 1) { if (tid < st) red[tid] = fmaxf(red[tid], red[tid + st]); __syncthreads(); }
  m = red[0]; __syncthreads();
  float e0 = __expf(s0 - m), e1 = __expf(s1 - m);
  aw[tid] = e0; aw[tid + 256] = e1;
  red[tid] = e0 + e1; __syncthreads();
  for (int st = 128; st; st >>= 1) { if (tid < st) red[tid] += red[tid + st]; __syncthreads(); }
  float inv = frcp(red[0]);
  __syncthreads();
  int wv = tid >> 6, l = tid & 63;
  int q = l & 7, tp = l >> 3;        // 8 col-groups x 8 t-slots
  const unsigned char* eb = enc8 + (size_t)b * T * H + y * 64 + q * 8;
  float a[8] = {};
  for (int it = 0; it < 16; it++) {
    int t = it * 32 + wv * 8 + tp;
    uint2 u = *(const uint2*)&eb[(size_t)t * H];
    float w = aw[t];
    a[0] += w * e4m3f(u.x & 0xFF);
    a[1] += w * e4m3f((u.x >> 8) & 0xFF);
    a[2] += w * e4m3f((u.x >> 16) & 0xFF);
    a[3] += w * e4m3f(u.x >> 24);
    a[4] += w * e4m3f(u.y & 0xFF);
    a[5] += w * e4m3f((u.y >> 8) & 0xFF);
    a[6] += w * e4m3f((u.y >> 16) & 0xFF);
    a[7] += w * e4m3f(u.y >> 24);
  }
#pragma unroll
  for (int j = 0; j < 8; j++) {
    a[j] += __shfl_xor(a[j], 8, 64);
    a[j] += __shfl_xor(a[j], 16, 64);
    a[j] += __shfl_xor(a[j], 32, 64);
  }
  __syncthreads();
  if (tp == 0) {
#pragma unroll
    for (int j = 0; j < 8; j++) red[wv * 64 + q * 8 + j] = a[j];
  }
  __syncthreads();
  if (tid < 64) {
    float val = (red[tid] + red[64 + tid] + red[128 + tid] + red[192 + tid]) * inv;
    xc[(size_t)b * K0 + E + y * 64 + tid] = f2bf(val);
  }
}

// ===== log-softmax finalize (last step) ====================================
__global__ __launch_bounds__(256) void k_lsB(const float* __restrict__ logits,
    const float* __restrict__ part, float* __restrict__ out, int s) {
  int b = blockIdx.x, ch = blockIdx.y, tid = threadIdx.x;
  __shared__ float red[256];
  float ssum = 0.f;
  for (int i = tid; i < V / 64; i += 256) ssum += part[i * 32 + b];
  red[tid] = ssum; __syncthreads();
  for (int st = 128; st; st >>= 1) { if (tid < st) red[tid] += red[tid + st]; __syncthreads(); }
  float lse = __logf(red[0]);
  const float* L = logits + (size_t)b * V + ch * 4000;
  float* O = out + ((size_t)b * S + s) * V + ch * 4000;
  for (int i = tid; i < 1000; i += 256) {
    float4 v = ((const float4*)L)[i];
    ((float4*)O)[i] = make_float4(v.x - lse, v.y - lse, v.z - lse, v.w - lse);
  }
}

// ===========================================================================
extern "C" void kernel_launch(void* const* d_in, const int* in_sizes, int n_in,
                              void* d_out, int out_size, void* d_ws, size_t ws_size,
                              hipStream_t stream) {
  const float* enc_out   = (const float*)d_in[0];
  const float* enc_h     = (const float*)d_in[1];
  const float* enc_c     = (const float*)d_in[2];
  const float* embedding = (const float*)d_in[3];
  const float* attn_W    = (const float*)d_in[4];
  const float* attn_b    = (const float*)d_in[5];
  const float* vvec      = (const float*)d_in[6];
  const float* Wih0      = (const float*)d_in[7];
  const float* Whh0      = (const float*)d_in[8];
  const float* bih0      = (const float*)d_in[9];
  const float* bhh0      = (const float*)d_in[10];
  const float* Wih1      = (const float*)d_in[11];
  const float* Whh1      = (const float*)d_in[12];
  const float* bih1      = (const float*)d_in[13];
  const float* bhh1      = (const float*)d_in[14];
  const float* genW      = (const float*)d_in[15];
  const float* genb      = (const float*)d_in[16];
  const int*   question  = (const int*)d_in[17];
  float* out = (float*)d_out;

  char* w = (char*)d_ws;
  auto alloc = [&](size_t bytes) { char* r = w; w += (bytes + 255) & ~(size_t)255; return r; };
  unsigned char*  Wbig8 = (unsigned char*)alloc((size_t)MG * H);
  unsigned short* Wc0   = (unsigned short*)alloc((size_t)4096 * K0 * 2);
  unsigned short* Wc1   = (unsigned short*)alloc((size_t)4096 * K1 * 2);
  unsigned char*  encb8 = (unsigned char*)alloc((size_t)B * T * H);
  unsigned char*  encp8 = (unsigned char*)alloc((size_t)B * T * H);
  unsigned char*  Wr8   = (unsigned char*)alloc((size_t)H * H);
  float* bcomb0 = (float*)alloc(4096 * 4);
  float* bcomb1 = (float*)alloc(4096 * 4);
  float* cbuf   = (float*)alloc((size_t)2 * B * H * 4);
  unsigned short* xc0[2] = {(unsigned short*)alloc((size_t)B * K0 * 2),
                            (unsigned short*)alloc((size_t)B * K0 * 2)};
  unsigned short* xc1[2] = {(unsigned short*)alloc((size_t)B * K1 * 2),
                            (unsigned short*)alloc((size_t)B * K1 * 2)};
  unsigned char*  hgen8 = (unsigned char*)alloc((size_t)B * H);
  float* hidproj = (float*)alloc((size_t)B * H * 4);
  float* scores  = (float*)alloc((size_t)B * T * 4);
  float* logits  = (float*)alloc((size_t)B * V * 4);
  float* part    = (float*)alloc((size_t)(V / 64) * 32 * 4);

  // one-time prep
  k_cast_gen<<<(int)(((size_t)MG * H / 4 + 255) / 256), 256, 0, stream>>>(genW, attn_W, Wbig8);
  k_cast_l0<<<4096, 256, 0, stream>>>(Wih0, Whh0, Wc0);
  k_cast_l1<<<4096, 256, 0, stream>>>(Wih1, Whh1, Wc1);
  k_cast_attnr<<<H * H / 4 / 256, 256, 0, stream>>>(attn_W, Wr8);
  k_bias<<<32, 256, 0, stream>>>(bih0, bhh0, bih1, bhh1, bcomb0, bcomb1);
  k_cast_enc<<<(B * T * H / 4) / 256, 256, 0, stream>>>(enc_out, encb8);
  k_init<<<(2 * B * H + 2 * B * 20 + 255) / 256, 256, 0, stream>>>(
      enc_h, enc_c, cbuf, xc0[0], xc0[1], xc1[0], hgen8);
  k_encproj_mfma<<<4096, 256, 0, stream>>>(Wr8, encb8, attn_b, encp8);
  // hidproj for step 0 from initial h1 (fp8 path, rows V..MG of Wbig8)
  k_gemm_out_fp8<<<H / 64, 256, 0, stream>>>(
      Wbig8 + (size_t)V * H, hgen8, nullptr, 0, nullptr, 0, hidproj, H, nullptr);

  for (int s = 0; s < S; s++) {
    int par = s & 1;
    // scores(s) + emb(s) — emb must precede lstm0's read of xc0[par]
    k_p1<<<544, 256, 0, stream>>>(encp8, hidproj, vvec, scores,
                                  embedding, question, xc0[par], s);
    k_ctx<<<dim3(B, 16), 256, 0, stream>>>(scores, encb8, xc0[par]);
    // lstm0 + rider: lsB(s-1) fills the idle half of the machine
    k_gemm_lstm<K0><<<512, 512, 0, stream>>>(
        Wc0, xc0[par], bcomb0, cbuf,
        xc0[par ^ 1], K0, KX,
        xc1[par], K1, 0,
        nullptr,
        1, logits, part, out, s);
    k_gemm_lstm<K1><<<256, 512, 0, stream>>>(
        Wc1, xc1[par], bcomb1, cbuf + B * H,
        xc1[par ^ 1], K1, H,
        nullptr, 0, 0,
        hgen8,
        0, nullptr, nullptr, nullptr, 0);
    k_gemm_out_fp8<<<MG / 64, 256, 0, stream>>>(
        Wbig8, hgen8, genb, V, logits, V, hidproj, H, part);
  }
  k_lsB<<<dim3(B, 8), 256, 0, stream>>>(logits, part, out, S - 1);
}

// Round 18
// 3860.177 us; speedup vs baseline: 1.0109x; 1.0109x over previous
//
#include <hip/hip_runtime.h>
#include <hip/hip_bf16.h>
#include <math.h>

#define DEVI static __device__ __forceinline__

namespace {
constexpr int B = 32, T = 512, H = 1024, E = 300, V = 32000, S = 50;
constexpr int KX = E + H;       // 1324
constexpr int K0 = 2368;        // KX + H + 20 zero-pad  (74 * 32)
constexpr int K1 = 2048;        // H + H                 (64 * 32)
constexpr int MG = V + H;       // 33024 = generator rows + attn-left rows
}

typedef __bf16 bf16x8 __attribute__((ext_vector_type(8)));
typedef float f32x4 __attribute__((ext_vector_type(4)));

DEVI float bf2f(unsigned short u) { union { unsigned int i; float f; } v; v.i = (unsigned int)u << 16; return v.f; }
DEVI unsigned short f2bf(float f) {
  union { float f; unsigned int i; } v; v.f = f;
  unsigned int x = v.i;
  return (unsigned short)((x + 0x7fffu + ((x >> 16) & 1u)) >> 16);
}
// f32 -> fp8 e4m3fn (OCP), RNE, saturate to +-448
DEVI unsigned char f2e4m3(float x) {
  union { float f; unsigned int u; } v;
  v.f = x;
  unsigned int s = (v.u >> 24) & 0x80u;
  v.u &= 0x7FFFFFFFu;
  if (v.f >= 448.0f) return (unsigned char)(s | 0x7E);
  if (v.f < 0.015625f) {
    int q = (int)rintf(v.f * 512.0f);
    return (unsigned char)(s | (unsigned int)q);
  }
  unsigned int u = v.u;
  unsigned int lsb = (u >> 20) & 1u;
  u += 0x0007FFFFu + lsb;
  unsigned int exp = (u >> 23) - 120u;
  unsigned int man = (u >> 20) & 7u;
  return (unsigned char)(s | (exp << 3) | man);
}
// fp8 e4m3 -> f32, exact for normals, subnormals, zero
DEVI float e4m3f(unsigned int u) {
  unsigned int bits = ((u & 0x80u) << 24) | ((u & 0x7Fu) << 20);
  union { unsigned int i; float f; } v; v.i = bits;
  return v.f * 0x1p120f;
}
#if __has_builtin(__builtin_amdgcn_rcpf)
DEVI float frcp(float x) { return __builtin_amdgcn_rcpf(x); }
#else
DEVI float frcp(float x) { return 1.0f / x; }
#endif
DEVI float sigm(float x) { return frcp(1.0f + __expf(-x)); }
DEVI float tanh_(float x) { return 1.0f - 2.0f * frcp(__expf(2.0f * x) + 1.0f); }

// ===== one-time weight casts ==============================================
__global__ __launch_bounds__(256) void k_cast_gen(const float* __restrict__ genW,
    const float* __restrict__ attn_W, unsigned char* __restrict__ Wbig8) {
  size_t i4 = ((size_t)blockIdx.x * 256 + threadIdx.x) * 4;
  if (i4 >= (size_t)MG * H) return;
  int row = (int)(i4 >> 10), k = (int)(i4 & 1023);
  const float* src = row < V ? &genW[((size_t)row << 10) + k]
                             : &attn_W[(size_t)(row - V) * (2 * H) + k];
  float4 v = *(const float4*)src;
  uchar4 o; o.x = f2e4m3(v.x); o.y = f2e4m3(v.y); o.z = f2e4m3(v.z); o.w = f2e4m3(v.w);
  *(uchar4*)&Wbig8[i4] = o;
}

__global__ __launch_bounds__(256) void k_cast_l0(const float* __restrict__ Wih,
    const float* __restrict__ Whh, unsigned short* __restrict__ Wc) {
  int m = blockIdx.x;                       // 4096 rows, m = n*4 + g
  int g = m & 3, n = m >> 2, srow = g * H + n;
  for (int i = threadIdx.x; i < K0 / 4; i += 256) {
    int k = i * 4;
    float4 v;
    if (k < KX) v = *(const float4*)&Wih[(size_t)srow * KX + k];
    else if (k < KX + H) v = *(const float4*)&Whh[(size_t)srow * H + (k - KX)];
    else v = make_float4(0.f, 0.f, 0.f, 0.f);
    ushort4 o; o.x = f2bf(v.x); o.y = f2bf(v.y); o.z = f2bf(v.z); o.w = f2bf(v.w);
    *(ushort4*)&Wc[(size_t)m * K0 + k] = o;
  }
}

__global__ __launch_bounds__(256) void k_cast_l1(const float* __restrict__ Wih,
    const float* __restrict__ Whh, unsigned short* __restrict__ Wc) {
  int m = blockIdx.x;
  int g = m & 3, n = m >> 2, srow = g * H + n;
  for (int i = threadIdx.x; i < K1 / 4; i += 256) {
    int k = i * 4;
    float4 v = (k < H) ? *(const float4*)&Wih[(size_t)srow * H + k]
                       : *(const float4*)&Whh[(size_t)srow * H + (k - H)];
    ushort4 o; o.x = f2bf(v.x); o.y = f2bf(v.y); o.z = f2bf(v.z); o.w = f2bf(v.w);
    *(ushort4*)&Wc[(size_t)m * K1 + k] = o;
  }
}

// attn_W right half -> fp8 [H][H] (for fp8 encproj MFMA)
__global__ __launch_bounds__(256) void k_cast_attnr(const float* __restrict__ attn_W,
                                                    unsigned char* __restrict__ Wr8) {
  size_t i4 = ((size_t)blockIdx.x * 256 + threadIdx.x) * 4;
  if (i4 >= (size_t)H * H) return;
  int n = (int)(i4 >> 10), k = (int)(i4 & 1023);
  float4 v = *(const float4*)&attn_W[(size_t)n * (2 * H) + H + k];
  uchar4 o; o.x = f2e4m3(v.x); o.y = f2e4m3(v.y); o.z = f2e4m3(v.z); o.w = f2e4m3(v.w);
  *(uchar4*)&Wr8[i4] = o;
}

__global__ void k_bias(const float* bih0, const float* bhh0,
                       const float* bih1, const float* bhh1,
                       float* bc0, float* bc1) {
  int idx = blockIdx.x * 256 + threadIdx.x;
  if (idx < 4096) { int g = idx & 3, n = idx >> 2; bc0[idx] = bih0[g * H + n] + bhh0[g * H + n]; }
  else if (idx < 8192) { int m = idx - 4096; int g = m & 3, n = m >> 2; bc1[m] = bih1[g * H + n] + bhh1[g * H + n]; }
}

// enc_out -> fp8 (used by encproj MFMA and per-step ctx reads)
__global__ __launch_bounds__(256) void k_cast_enc(const float* __restrict__ src,
    unsigned char* __restrict__ dst8) {
  size_t i4 = ((size_t)blockIdx.x * 256 + threadIdx.x) * 4;
  if (i4 >= (size_t)B * T * H) return;
  float4 v = *(const float4*)&src[i4];
  uchar4 o8; o8.x = f2e4m3(v.x); o8.y = f2e4m3(v.y); o8.z = f2e4m3(v.z); o8.w = f2e4m3(v.w);
  *(uchar4*)&dst8[i4] = o8;
}

// ===== initial state =======================================================
__global__ __launch_bounds__(256) void k_init(const float* __restrict__ enc_h,
    const float* __restrict__ enc_c, float* __restrict__ cbuf,
    unsigned short* __restrict__ xc0_0, unsigned short* __restrict__ xc0_1,
    unsigned short* __restrict__ xc1_0, unsigned char* __restrict__ hgen8) {
  int idx = blockIdx.x * 256 + threadIdx.x;
  if (idx < 2 * B * H) {
    int l = idx >> 15, r = idx & 32767, b = r >> 10, hh = r & 1023;
    int half = hh >> 9, hr = hh & 511;
    int src = (2 * l + half) * B * (H / 2) + b * (H / 2) + hr;
    cbuf[idx] = enc_c[src];
    float hv = enc_h[src];
    if (l == 0) xc0_0[(size_t)b * K0 + KX + hh] = f2bf(hv);
    else { xc1_0[(size_t)b * K1 + H + hh] = f2bf(hv); hgen8[(size_t)b * H + hh] = f2e4m3(hv); }
  } else if (idx < 2 * B * H + 2 * B * 20) {
    int j = idx - 2 * B * H;
    int p = j / (B * 20), rr = j % (B * 20), b = rr / 20, kk = rr % 20;
    (p ? xc0_1 : xc0_0)[(size_t)b * K0 + KX + H + kk] = 0;
  }
}

// ===== fp8 GEMM core (K=1024): 16 rows x 32 batch per wave =================
DEVI void gemm_tile_fp8(const unsigned char* __restrict__ W, const unsigned char* __restrict__ X,
                        int m0w, int lane, f32x4& acc0, f32x4& acc1) {
  const unsigned char* Wp = W + (size_t)(m0w + (lane & 15)) * 1024 + (lane >> 4) * 8;
  const unsigned char* Xp = X + (size_t)(lane & 15) * 1024 + (lane >> 4) * 8;
#pragma unroll 4
  for (int k0 = 0; k0 < 1024; k0 += 32) {
    long a  = *(const long*)(Wp + k0);
    long b0 = *(const long*)(Xp + k0);
    long b1 = *(const long*)(Xp + 16 * 1024 + k0);
    acc0 = __builtin_amdgcn_mfma_f32_16x16x32_fp8_fp8(a, b0, acc0, 0, 0, 0);
    acc1 = __builtin_amdgcn_mfma_f32_16x16x32_fp8_fp8(a, b1, acc1, 0, 0, 0);
  }
}

// ===== one-time enc projection: fp8 MFMA GEMM, fp8 output ==================
__global__ __launch_bounds__(256) void k_encproj_mfma(const unsigned char* __restrict__ Wr8,
    const unsigned char* __restrict__ Xb8, const float* __restrict__ attn_b,
    unsigned char* __restrict__ encp8) {
  int bid = blockIdx.x;
  int m0 = (bid & 255) * 64;
  int n0 = (bid >> 8) * 64;
  int wv = threadIdx.x >> 6, lane = threadIdx.x & 63;
  int n0w = n0 + wv * 16;
  const unsigned char* Wp = Wr8 + (size_t)(n0w + (lane & 15)) * H + (lane >> 4) * 8;
  const unsigned char* Xp = Xb8 + (size_t)(m0 + (lane & 15)) * H + (lane >> 4) * 8;
  f32x4 acc[4] = {{0.f,0.f,0.f,0.f},{0.f,0.f,0.f,0.f},{0.f,0.f,0.f,0.f},{0.f,0.f,0.f,0.f}};
#pragma unroll 4
  for (int k0 = 0; k0 < H; k0 += 32) {
    long a = *(const long*)(Wp + k0);
#pragma unroll
    for (int g = 0; g < 4; g++) {
      long b = *(const long*)(Xp + (size_t)g * 16 * H + k0);
      acc[g] = __builtin_amdgcn_mfma_f32_16x16x32_fp8_fp8(a, b, acc[g], 0, 0, 0);
    }
  }
  int nbx = n0w + (lane >> 4) * 4;
  f32x4 bi = *(const f32x4*)&attn_b[nbx];
#pragma unroll
  for (int g = 0; g < 4; g++) {
    int m = m0 + g * 16 + (lane & 15);
    f32x4 o = acc[g] + bi;
    uchar4 ob; ob.x = f2e4m3(o[0]); ob.y = f2e4m3(o[1]); ob.z = f2e4m3(o[2]); ob.w = f2e4m3(o[3]);
    *(uchar4*)&encp8[(size_t)m * H + nbx] = ob;
  }
}

// rows < M0 -> out0 (+bias, + optional expsum partials); rows >= M0 -> out1.
__global__ __launch_bounds__(256, 4) void k_gemm_out_fp8(const unsigned char* __restrict__ W,
    const unsigned char* __restrict__ X, const float* __restrict__ bias, int M0,
    float* __restrict__ out0, int ld0, float* __restrict__ out1, int ld1,
    float* __restrict__ part) {
  __shared__ float esum[4][32];
  int wv = threadIdx.x >> 6, lane = threadIdx.x & 63;
  int m0w = blockIdx.x * 64 + wv * 16;
  f32x4 acc0 = {0.f, 0.f, 0.f, 0.f}, acc1 = acc0;
  gemm_tile_fp8(W, X, m0w, lane, acc0, acc1);
  int r0 = m0w + (lane >> 4) * 4;
  int b = lane & 15;
  float s0 = 0.f, s1 = 0.f;
  if (r0 < M0) {
    f32x4 bi = *(const f32x4*)&bias[r0];
    f32x4 o0 = acc0 + bi, o1 = acc1 + bi;
    *(f32x4*)&out0[(size_t)b * ld0 + r0] = o0;
    *(f32x4*)&out0[(size_t)(b + 16) * ld0 + r0] = o1;
    s0 = __expf(o0[0]) + __expf(o0[1]) + __expf(o0[2]) + __expf(o0[3]);
    s1 = __expf(o1[0]) + __expf(o1[1]) + __expf(o1[2]) + __expf(o1[3]);
  } else {
    int r = r0 - M0;
    *(f32x4*)&out1[(size_t)b * ld1 + r] = acc0;
    *(f32x4*)&out1[(size_t)(b + 16) * ld1 + r] = acc1;
  }
  if (part != nullptr && blockIdx.x < V / 64) {
    s0 += __shfl_xor(s0, 16, 64); s0 += __shfl_xor(s0, 32, 64);
    s1 += __shfl_xor(s1, 16, 64); s1 += __shfl_xor(s1, 32, 64);
    if (lane < 16) { esum[wv][lane] = s0; esum[wv][lane + 16] = s1; }
    __syncthreads();
    if (threadIdx.x < 32)
      part[blockIdx.x * 32 + threadIdx.x] =
          esum[0][threadIdx.x] + esum[1][threadIdx.x] + esum[2][threadIdx.x] + esum[3][threadIdx.x];
  }
}

// LSTM: 16 rows/block, 512 threads = 8 waves splitting K (interleaved 32-chunks).
template <int K>
__global__ __launch_bounds__(512, 2) void k_gemm_lstm(const unsigned short* __restrict__ W,
    const unsigned short* __restrict__ X, const float* __restrict__ bcomb,
    float* __restrict__ c,
    unsigned short* __restrict__ hA, int ldA_, int offA,
    unsigned short* __restrict__ hB, int ldB_, int offB,
    unsigned char* __restrict__ h8) {
  __shared__ f32x4 red[8][64][2];   // 16 KB
  int wv = threadIdx.x >> 6, lane = threadIdx.x & 63;
  int m0w = blockIdx.x * 16;
  const unsigned short* Wp = W + (size_t)(m0w + (lane & 15)) * K + (lane >> 4) * 8;
  const unsigned short* Xp = X + (size_t)(lane & 15) * K + (lane >> 4) * 8;
  f32x4 acc0 = {0.f, 0.f, 0.f, 0.f}, acc1 = acc0;
#pragma unroll 2
  for (int k0 = wv * 32; k0 < K; k0 += 256) {
    bf16x8 a  = *(const bf16x8*)(Wp + k0);
    bf16x8 b0 = *(const bf16x8*)(Xp + k0);
    bf16x8 b1 = *(const bf16x8*)(Xp + 16 * K + k0);
    acc0 = __builtin_amdgcn_mfma_f32_16x16x32_bf16(a, b0, acc0, 0, 0, 0);
    acc1 = __builtin_amdgcn_mfma_f32_16x16x32_bf16(a, b1, acc1, 0, 0, 0);
  }
  red[wv][lane][0] = acc0;
  red[wv][lane][1] = acc1;
  __syncthreads();
  if (wv == 0) {
    acc0 = red[0][lane][0] + red[1][lane][0] + red[2][lane][0] + red[3][lane][0]
         + red[4][lane][0] + red[5][lane][0] + red[6][lane][0] + red[7][lane][0];
    acc1 = red[0][lane][1] + red[1][lane][1] + red[2][lane][1] + red[3][lane][1]
         + red[4][lane][1] + red[5][lane][1] + red[6][lane][1] + red[7][lane][1];
    int r0 = m0w + (lane >> 4) * 4;
    int n = r0 >> 2;
    f32x4 bi = *(const f32x4*)&bcomb[r0];
#pragma unroll
    for (int f = 0; f < 2; f++) {
      f32x4 g = f ? acc1 : acc0;
      int b = (lane & 15) + f * 16;
      float gi = g[0] + bi[0], gf = g[1] + bi[1];
      float gg = g[2] + bi[2], go = g[3] + bi[3];
      float cp = c[(size_t)b * H + n];
      float c2 = sigm(gf) * cp + sigm(gi) * tanh_(gg);
      c[(size_t)b * H + n] = c2;
      float h2 = sigm(go) * tanh_(c2);
      unsigned short hb = f2bf(h2);
      hA[(size_t)b * ldA_ + offA + n] = hb;
      if (hB) hB[(size_t)b * ldB_ + offB + n] = hb;
      if (h8) h8[(size_t)b * H + n] = f2e4m3(h2);
    }
  }
}

// ===== P1: scores (fp8 encp, 8 t/wave) + lsB(s-1) + embedding gather =======
// grid 800: [0,512) scores; [512,768) lsB(s-1); [768,800) emb.
__global__ __launch_bounds__(256, 4) void k_p1(const unsigned char* __restrict__ encp8,
    const float* __restrict__ hidproj, const float* __restrict__ vvec,
    float* __restrict__ scores,
    const float* __restrict__ logits, const float* __restrict__ part,
    float* __restrict__ out,
    const float* __restrict__ embedding, const int* __restrict__ question,
    unsigned short* __restrict__ xc, int s) {
  int bx = blockIdx.x, tid = threadIdx.x;
  if (bx < 512) {
    int wv = tid >> 6, lane = tid & 63;
    int wid0 = bx * 32 + wv * 8;
    int b = wid0 >> 9;
    const float* hp = hidproj + (size_t)b * H + lane * 16;
    const float* vp = vvec + lane * 16;
    float4 h4[4], v4[4];
#pragma unroll
    for (int i = 0; i < 4; i++) { h4[i] = *(const float4*)&hp[i * 4]; v4[i] = *(const float4*)&vp[i * 4]; }
#pragma unroll
    for (int j = 0; j < 8; j++) {
      const unsigned char* ep = encp8 + (size_t)(wid0 + j) * H + lane * 16;
      uint4 u = *(const uint4*)ep;
      float acc = 0.f;
      unsigned int ws[4] = {u.x, u.y, u.z, u.w};
#pragma unroll
      for (int i = 0; i < 4; i++) {
        unsigned int wd = ws[i];
        acc += v4[i].x * tanh_(e4m3f(wd & 0xFF) + h4[i].x);
        acc += v4[i].y * tanh_(e4m3f((wd >> 8) & 0xFF) + h4[i].y);
        acc += v4[i].z * tanh_(e4m3f((wd >> 16) & 0xFF) + h4[i].z);
        acc += v4[i].w * tanh_(e4m3f(wd >> 24) + h4[i].w);
      }
#pragma unroll
      for (int off = 32; off; off >>= 1) acc += __shfl_xor(acc, off, 64);
      if (lane == 0) scores[wid0 + j] = acc;
    }
  } else if (bx < 768) {
    if (s == 0) return;
    __shared__ float red[256];
    int idx = bx - 512;
    int b = idx >> 3, ch = idx & 7;
    float ssum = 0.f;
    for (int i = tid; i < V / 64; i += 256) ssum += part[i * 32 + b];
    red[tid] = ssum; __syncthreads();
    for (int st = 128; st; st >>= 1) { if (tid < st) red[tid] += red[tid + st]; __syncthreads(); }
    float lse = __logf(red[0]);
    const float* L = logits + (size_t)b * V + ch * 4000;
    float* O = out + ((size_t)b * S + (s - 1)) * V + ch * 4000;
    for (int i = tid; i < 1000; i += 256) {
      float4 v = ((const float4*)L)[i];
      ((float4*)O)[i] = make_float4(v.x - lse, v.y - lse, v.z - lse, v.w - lse);
    }
  } else {
    int b = bx - 768;
    int tok = question[b * S + s];
    for (int e = tid; e < E; e += 256)
      xc[(size_t)b * K0 + e] = f2bf(embedding[(size_t)tok * E + e]);
  }
}

// ===== ctx: softmax over T + weighted sum of fp8 enc columns ===============
__global__ __launch_bounds__(256, 4) void k_ctx(const float* __restrict__ scores,
    const unsigned char* __restrict__ enc8, unsigned short* __restrict__ xc) {
  int b = blockIdx.x, y = blockIdx.y, tid = threadIdx.x;
  __shared__ float aw[T];
  __shared__ float red[256];
  float s0 = scores[b * T + tid], s1 = scores[b * T + 256 + tid];
  float m = fmaxf(s0, s1);
  red[tid] = m; __syncthreads();
  for (int st = 128; st; st >>= 1) { if (tid < st) red[tid] = fmaxf(red[tid], red[tid + st]); __syncthreads(); }
  m = red[0]; __syncthreads();
  float e0 = __expf(s0 - m), e1 = __expf(s1 - m);
  aw[tid] = e0; aw[tid + 256] = e1;
  red[tid] = e0 + e1; __syncthreads();
  for (int st = 128; st; st >>= 1) { if (tid < st) red[tid] += red[tid + st]; __syncthreads(); }
  float inv = frcp(red[0]);
  __syncthreads();
  int wv = tid >> 6, l = tid & 63;
  int q = l & 7, tp = l >> 3;        // 8 col-groups x 8 t-slots
  const unsigned char* eb = enc8 + (size_t)b * T * H + y * 64 + q * 8;
  float a[8] = {};
  for (int it = 0; it < 16; it++) {
    int t = it * 32 + wv * 8 + tp;
    uint2 u = *(const uint2*)&eb[(size_t)t * H];
    float w = aw[t];
    a[0] += w * e4m3f(u.x & 0xFF);
    a[1] += w * e4m3f((u.x >> 8) & 0xFF);
    a[2] += w * e4m3f((u.x >> 16) & 0xFF);
    a[3] += w * e4m3f(u.x >> 24);
    a[4] += w * e4m3f(u.y & 0xFF);
    a[5] += w * e4m3f((u.y >> 8) & 0xFF);
    a[6] += w * e4m3f((u.y >> 16) & 0xFF);
    a[7] += w * e4m3f(u.y >> 24);
  }
#pragma unroll
  for (int j = 0; j < 8; j++) {
    a[j] += __shfl_xor(a[j], 8, 64);
    a[j] += __shfl_xor(a[j], 16, 64);
    a[j] += __shfl_xor(a[j], 32, 64);
  }
  __syncthreads();
  if (tp == 0) {
#pragma unroll
    for (int j = 0; j < 8; j++) red[wv * 64 + q * 8 + j] = a[j];
  }
  __syncthreads();
  if (tid < 64) {
    float val = (red[tid] + red[64 + tid] + red[128 + tid] + red[192 + tid]) * inv;
    xc[(size_t)b * K0 + E + y * 64 + tid] = f2bf(val);
  }
}

// ===== log-softmax finalize (last step) ====================================
__global__ __launch_bounds__(256) void k_lsB(const float* __restrict__ logits,
    const float* __restrict__ part, float* __restrict__ out, int s) {
  int b = blockIdx.x, ch = blockIdx.y, tid = threadIdx.x;
  __shared__ float red[256];
  float ssum = 0.f;
  for (int i = tid; i < V / 64; i += 256) ssum += part[i * 32 + b];
  red[tid] = ssum; __syncthreads();
  for (int st = 128; st; st >>= 1) { if (tid < st) red[tid] += red[tid + st]; __syncthreads(); }
  float lse = __logf(red[0]);
  const float* L = logits + (size_t)b * V + ch * 4000;
  float* O = out + ((size_t)b * S + s) * V + ch * 4000;
  for (int i = tid; i < 1000; i += 256) {
    float4 v = ((const float4*)L)[i];
    ((float4*)O)[i] = make_float4(v.x - lse, v.y - lse, v.z - lse, v.w - lse);
  }
}

// ===========================================================================
extern "C" void kernel_launch(void* const* d_in, const int* in_sizes, int n_in,
                              void* d_out, int out_size, void* d_ws, size_t ws_size,
                              hipStream_t stream) {
  const float* enc_out   = (const float*)d_in[0];
  const float* enc_h     = (const float*)d_in[1];
  const float* enc_c     = (const float*)d_in[2];
  const float* embedding = (const float*)d_in[3];
  const float* attn_W    = (const float*)d_in[4];
  const float* attn_b    = (const float*)d_in[5];
  const float* vvec      = (const float*)d_in[6];
  const float* Wih0      = (const float*)d_in[7];
  const float* Whh0      = (const float*)d_in[8];
  const float* bih0      = (const float*)d_in[9];
  const float* bhh0      = (const float*)d_in[10];
  const float* Wih1      = (const float*)d_in[11];
  const float* Whh1      = (const float*)d_in[12];
  const float* bih1      = (const float*)d_in[13];
  const float* bhh1      = (const float*)d_in[14];
  const float* genW      = (const float*)d_in[15];
  const float* genb      = (const float*)d_in[16];
  const int*   question  = (const int*)d_in[17];
  float* out = (float*)d_out;

  char* w = (char*)d_ws;
  auto alloc = [&](size_t bytes) { char* r = w; w += (bytes + 255) & ~(size_t)255; return r; };
  unsigned char*  Wbig8 = (unsigned char*)alloc((size_t)MG * H);
  unsigned short* Wc0   = (unsigned short*)alloc((size_t)4096 * K0 * 2);
  unsigned short* Wc1   = (unsigned short*)alloc((size_t)4096 * K1 * 2);
  unsigned char*  encb8 = (unsigned char*)alloc((size_t)B * T * H);
  unsigned char*  encp8 = (unsigned char*)alloc((size_t)B * T * H);
  unsigned char*  Wr8   = (unsigned char*)alloc((size_t)H * H);
  float* bcomb0 = (float*)alloc(4096 * 4);
  float* bcomb1 = (float*)alloc(4096 * 4);
  float* cbuf   = (float*)alloc((size_t)2 * B * H * 4);
  unsigned short* xc0[2] = {(unsigned short*)alloc((size_t)B * K0 * 2),
                            (unsigned short*)alloc((size_t)B * K0 * 2)};
  unsigned short* xc1[2] = {(unsigned short*)alloc((size_t)B * K1 * 2),
                            (unsigned short*)alloc((size_t)B * K1 * 2)};
  unsigned char*  hgen8 = (unsigned char*)alloc((size_t)B * H);
  float* hidproj = (float*)alloc((size_t)B * H * 4);
  float* scores  = (float*)alloc((size_t)B * T * 4);
  float* logits  = (float*)alloc((size_t)B * V * 4);
  float* part    = (float*)alloc((size_t)(V / 64) * 32 * 4);

  // one-time prep
  k_cast_gen<<<(int)(((size_t)MG * H / 4 + 255) / 256), 256, 0, stream>>>(genW, attn_W, Wbig8);
  k_cast_l0<<<4096, 256, 0, stream>>>(Wih0, Whh0, Wc0);
  k_cast_l1<<<4096, 256, 0, stream>>>(Wih1, Whh1, Wc1);
  k_cast_attnr<<<H * H / 4 / 256, 256, 0, stream>>>(attn_W, Wr8);
  k_bias<<<32, 256, 0, stream>>>(bih0, bhh0, bih1, bhh1, bcomb0, bcomb1);
  k_cast_enc<<<(B * T * H / 4) / 256, 256, 0, stream>>>(enc_out, encb8);
  k_init<<<(2 * B * H + 2 * B * 20 + 255) / 256, 256, 0, stream>>>(
      enc_h, enc_c, cbuf, xc0[0], xc0[1], xc1[0], hgen8);
  k_encproj_mfma<<<4096, 256, 0, stream>>>(Wr8, encb8, attn_b, encp8);
  // hidproj for step 0 from initial h1 (fp8 path, rows V..MG of Wbig8)
  k_gemm_out_fp8<<<H / 64, 256, 0, stream>>>(
      Wbig8 + (size_t)V * H, hgen8, nullptr, 0, nullptr, 0, hidproj, H, nullptr);

  for (int s = 0; s < S; s++) {
    int par = s & 1;
    k_p1<<<800, 256, 0, stream>>>(encp8, hidproj, vvec, scores,
                                  logits, part, out, embedding, question, xc0[par], s);
    k_ctx<<<dim3(B, 16), 256, 0, stream>>>(scores, encb8, xc0[par]);
    k_gemm_lstm<K0><<<4096 / 16, 512, 0, stream>>>(
        Wc0, xc0[par], bcomb0, cbuf,
        xc0[par ^ 1], K0, KX,        // h0n -> next step's layer-0 recurrent slot
        xc1[par], K1, 0,             // h0n -> layer-1 input slot (this step)
        nullptr);
    k_gemm_lstm<K1><<<4096 / 16, 512, 0, stream>>>(
        Wc1, xc1[par], bcomb1, cbuf + B * H,
        xc1[par ^ 1], K1, H,         // h1n -> next step's layer-1 recurrent slot
        nullptr, 0, 0,
        hgen8);                      // h1n (fp8) -> generator/hidproj input
    k_gemm_out_fp8<<<MG / 64, 256, 0, stream>>>(
        Wbig8, hgen8, genb, V, logits, V, hidproj, H, part);
  }
  k_lsB<<<dim3(B, 8), 256, 0, stream>>>(logits, part, out, S - 1);
}